// Round 16
// baseline (85.264 us; speedup 1.0000x reference)
//
#include <hip/hip_runtime.h>
#include <hip/hip_bf16.h>
#include <stdint.h>

typedef __bf16 bf16_t;
typedef bf16_t bf16x8 __attribute__((ext_vector_type(8)));
typedef float f32x4 __attribute__((ext_vector_type(4)));

#define DEVI static __device__ __forceinline__

constexpr int NB = 32, CIN = 256, COUT = 256, KNUM = 6, ET = 3, TDIM = 64, VV = 25;
constexpr int KD   = KNUM * CIN;       // 1536 contraction dim (k,ci)
constexpr long OUT0 = (long)NB * COUT * TDIM * VV;  // 13107200 (x_sum elems)
constexpr int ACNT = ET * VV * VV;     // 1875 (A copy)

// wp3: W in fragment-order. 24 steps x 2048 chunks x 16B = 768 KB. (R7 layout)
constexpr int NSTEP = 24;              // 4 cb x 6 k
constexpr int WP3_CHUNKS = NSTEP * 2048;
constexpr size_t WP3_BYTES  = (size_t)WP3_CHUNKS * 16;      // 768 KB
constexpr size_t BIAS_OFF   = WP3_BYTES;
constexpr size_t BIAS_BYTES = (size_t)NB * VV * COUT * 4;   // bias [n][w][c] f32
constexpr size_t WS_NEED    = BIAS_OFF + BIAS_BYTES;

DEVI unsigned packbf(float lo, float hi) {
  unsigned short a = __builtin_bit_cast(unsigned short, (bf16_t)lo);
  unsigned short b = __builtin_bit_cast(unsigned short, (bf16_t)hi);
  return ((unsigned)b << 16) | (unsigned)a;
}

// ---------------- prep: wp3 fragment-layout + bias table + A copy ----------
__global__ __launch_bounds__(256) void prep_kernel(
    const float* __restrict__ A, const float* __restrict__ Bm,
    const float* __restrict__ lam_p, const float* __restrict__ W,
    const float* __restrict__ bvec, bf16_t* __restrict__ wp3,
    float* __restrict__ biasmat, float* __restrict__ outA)
{
  int idx = blockIdx.x * 256 + threadIdx.x;
  constexpr int S1 = WP3_CHUNKS;            // 49152 (one 16B chunk per thread)
  constexpr int S2 = S1 + NB * VV * COUT;   // +204800
  constexpr int S3 = S2 + ACNT;
  if (idx < S1) {
    int s  = idx >> 11;
    int r  = idx & 2047;
    int mi = r >> 7;
    int kk = (r >> 6) & 1;
    int ln = r & 63;
    int lg = ln >> 4, lw = ln & 15;
    int cb = s / 6, k = s - cb * 6;
    int cibase = cb * 64 + (lg + 4 * kk) * 8;
    int col = (k << 8) + mi * 16 + lw;
    bf16_t* dst = wp3 + ((long)idx << 3);
    #pragma unroll
    for (int e = 0; e < 8; ++e)
      dst[e] = (bf16_t)W[(cibase + e) * KD + col];
  } else if (idx < S2) {
    // bias[n][w][c] = sum_k b[k*256+c] * S[n,k,w],  S = col-sum of M (lam folded)
    int j = idx - S1;
    int c = j & 255;
    int nw = j >> 8;
    int w = nw % VV;
    int n = nw / VV;
    float lam = lam_p[0];
    float s = 0.f;
    for (int k = 0; k < KNUM; ++k) {
      float sk = 0.f;
      if (k < ET) {
        for (int v = 0; v < VV; ++v) sk += A[(k * VV + v) * VV + w];
      } else {
        for (int v = 0; v < VV; ++v) sk += Bm[(((n * ET) + (k - ET)) * VV + v) * VV + w];
        sk *= lam;
      }
      s += bvec[(k << 8) + c] * sk;
    }
    biasmat[j] = s;
  } else if (idx < S3) {
    int j = idx - S2;
    outA[j] = A[j];   // second tuple output: A passthrough
  }
}

// ---------------- fused kernel (R15 + af2a moved after barrier) --------------
// Per step (cb,k): MFMA#1 Xs x Ms -> Bs[buf] (XOR-swizzled, dbuf); ONE
// barrier (NOTHING global pending at it); then af2a load issued post-barrier,
// MFMA#2 kk=0, af2b at use, MFMA#2 kk=1. Loads stall only their own wave
// (TLP-covered at 4 waves/SIMD), never the barrier.
__global__ __launch_bounds__(512, 4) void fused_kernel(
    const float* __restrict__ x, const float* __restrict__ A,
    const float* __restrict__ Bm, const float* __restrict__ lam_p,
    const bf16_t* __restrict__ wp3, const float* __restrict__ biasmat,
    float* __restrict__ out)
{
  __shared__ __align__(16) bf16_t Bs[2 * 128 * 64];  // 32 KB dbuf, rows 128B, XOR-swz
  __shared__ __align__(16) bf16_t Xs[256 * 32];      // 16 KB [row=dt*64+ci][v] swizzled
  __shared__ __align__(16) bf16_t Ms[KNUM * 32 * 32];// 12 KB [k][w][v] swizzled, zero-pad

  const int b = blockIdx.x;
  const int n = b >> 4;                  // 0..31
  const int t0 = (b & 15) << 2;          // t-group of 4
  const int tid = threadIdx.x;
  const int wv = tid >> 6, ln = tid & 63;
  const int lw = ln & 15, lg = ln >> 4;
  const float lam = lam_p[0];

  // stage Ms once: row R=k*32+w (64B), group-XOR sw2=(w&3)^((w>>2)&3)
  for (int i = tid; i < KNUM * 32 * 32; i += 512) {
    int R = i >> 5, v = i & 31;
    int k = i >> 10, w = (i >> 5) & 31;
    float val = 0.f;
    if (w < VV && v < VV)
      val = (k < ET) ? A[(k * VV + v) * VV + w]
                     : lam * Bm[(((n * ET) + (k - ET)) * VV + v) * VV + w];
    int sw2 = (w & 3) ^ ((w >> 2) & 3);
    int byteoff = R * 64 + ((((v >> 3) ^ sw2) & 3) << 4) + ((v & 7) << 1);
    *(bf16_t*)((char*)Ms + byteoff) = (bf16_t)val;
  }

  f32x4 acc[4][4] = {};
  const int m_base = (wv >> 1) * 64;
  const int mb4 = (wv >> 1) * 4;         // mi base for A-fragments
  const int n_base = (wv & 1) * 64;
  const f32x4 z4 = {0.f, 0.f, 0.f, 0.f};
  const int msw2 = (lw & 3) ^ ((lw >> 2) & 3);   // Ms read swizzle

  #pragma unroll 1
  for (int cb = 0; cb < 4; ++cb) {
    __syncthreads();   // all waves done reading previous cb's Xs
    // stage Xs (R7 verbatim): rows dt*64+ci, group-XOR swizzle
    if (tid < 256) {
      int ci = tid >> 2, dt = tid & 3;
      const float* xp = x + ((long)(n * CIN + cb * 64 + ci) * TDIM + t0 + dt) * VV;
      float xv[25];
      #pragma unroll
      for (int v = 0; v < VV; ++v) xv[v] = xp[v];
      int row = dt * 64 + ci;
      int sw = (row & 3) ^ ((row >> 2) & 3);
      #pragma unroll
      for (int g = 0; g < 4; ++g) {
        char* base = (char*)Xs + row * 64 + ((g ^ sw) & 3) * 16;
        #pragma unroll
        for (int p = 0; p < 4; ++p) {
          int v0 = g * 8 + p * 2;
          float lo = (v0     < VV) ? xv[v0 < VV ? v0 : 0]     : 0.f;
          float hi = (v0 + 1 < VV) ? xv[v0 + 1 < VV ? v0 + 1 : 0] : 0.f;
          *(unsigned*)(base + p * 4) = packbf(lo, hi);
        }
      }
    }
    __syncthreads();   // Xs visible

    #pragma unroll 1
    for (int k = 0; k < KNUM; ++k) {
      const int s = cb * 6 + k;
      const int buf = (s & 1) * (128 * 64);
      const bf16_t* wpS = wp3 + (((long)s * 2048 + (long)mb4 * 128 + ln) << 3);

      // MFMA#1: Xs x Ms -> Bs[buf]   (no global loads in flight here)
      bf16x8 mb0 = *(const bf16x8*)((const char*)Ms + (k * 32 + lw) * 64 + (((lg ^ msw2) & 3) << 4));
      bf16x8 mb1 = *(const bf16x8*)((const char*)Ms + (k * 32 + 16 + lw) * 64 + (((lg ^ msw2) & 3) << 4));
      #pragma unroll
      for (int rt = 0; rt < 2; ++rt) {
        int arow = wv * 32 + rt * 16 + lw;
        int sw = (arow & 3) ^ ((arow >> 2) & 3);
        int off = ((lg ^ sw) & 3) << 4;
        bf16x8 af = *(const bf16x8*)((const char*)Xs + arow * 64 + off);
        f32x4 d0 = __builtin_amdgcn_mfma_f32_16x16x32_bf16(af, mb0, z4, 0, 0, 0);
        f32x4 d1 = __builtin_amdgcn_mfma_f32_16x16x32_bf16(af, mb1, z4, 0, 0, 0);
        int rbase = wv * 32 + rt * 16 + (lg << 2);
        int dt = rbase >> 6, ci0 = rbase & 63;
        int r0 = dt * 32 + lw;
        int g0 = ((ci0 >> 3) ^ (r0 & 7)) & 7;
        char* c0 = (char*)(Bs + buf) + r0 * 128 + (g0 << 4) + ((ci0 << 1) & 15);
        *(unsigned*)(c0)     = packbf(d0[0], d0[1]);
        *(unsigned*)(c0 + 4) = packbf(d0[2], d0[3]);
        char* c1 = (char*)(Bs + buf) + (r0 + 16) * 128 + (g0 << 4) + ((ci0 << 1) & 15);
        *(unsigned*)(c1)     = packbf(d1[0], d1[1]);
        *(unsigned*)(c1 + 4) = packbf(d1[2], d1[3]);
      }
      __syncthreads();   // Bs[buf] ready; barrier drain is cheap (vmcnt clean)

      __builtin_amdgcn_s_setprio(1);
      // af2a load issued POST-barrier: stalls only this wave, TLP covers it
      {
        bf16x8 af2a[4];
        #pragma unroll
        for (int i = 0; i < 4; ++i)
          af2a[i] = *(const bf16x8*)(wpS + ((i * 128) << 3));
        bf16x8 bf2[4];
        #pragma unroll
        for (int j = 0; j < 4; ++j) {
          int rr = n_base + j * 16 + lw;
          int gg = (lg ^ (rr & 7)) & 7;
          bf2[j] = *(const bf16x8*)((const char*)(Bs + buf) + rr * 128 + (gg << 4));
        }
        #pragma unroll
        for (int i = 0; i < 4; ++i)
          #pragma unroll
          for (int j = 0; j < 4; ++j)
            acc[i][j] = __builtin_amdgcn_mfma_f32_16x16x32_bf16(af2a[i], bf2[j], acc[i][j], 0, 0, 0);
      }
      // MFMA#2 kk=1 (A-frags loaded at use)
      {
        bf16x8 af2b[4];
        #pragma unroll
        for (int i = 0; i < 4; ++i)
          af2b[i] = *(const bf16x8*)(wpS + ((i * 128 + 64) << 3));
        bf16x8 bf2[4];
        #pragma unroll
        for (int j = 0; j < 4; ++j) {
          int rr = n_base + j * 16 + lw;
          int gg = ((4 + lg) ^ (rr & 7)) & 7;
          bf2[j] = *(const bf16x8*)((const char*)(Bs + buf) + rr * 128 + (gg << 4));
        }
        #pragma unroll
        for (int i = 0; i < 4; ++i)
          #pragma unroll
          for (int j = 0; j < 4; ++j)
            acc[i][j] = __builtin_amdgcn_mfma_f32_16x16x32_bf16(af2b[i], bf2[j], acc[i][j], 0, 0, 0);
      }
      __builtin_amdgcn_s_setprio(0);
      __syncthreads();   // all waves done reading Bs[buf] before next overwrite
    }
  }

  // epilogue: C/D map col=lane&15, row=(lane>>4)*4+reg [m89-verified]
  #pragma unroll
  for (int j = 0; j < 4; ++j) {
    int colb = n_base + j * 16 + lw;         // 0..127
    int dt = colb >> 5, w = colb & 31;
    if (w < VV) {
      float* ob = out + (long)n * 409600 + (t0 + dt) * 25 + w;
      const float* brow = biasmat + (n * 25 + w) * 256;
      #pragma unroll
      for (int i = 0; i < 4; ++i) {
        int mb = m_base + i * 16 + (lg << 2);
        #pragma unroll
        for (int r = 0; r < 4; ++r) {
          int m = mb + r;
          ob[(long)m * 1600] = acc[i][j][r] + brow[m];
        }
      }
    }
  }
}

// ---------------- ws-free fp32 fallback (insurance) ----------------
__global__ __launch_bounds__(256) void fallback_kernel(
    const float* __restrict__ x, const float* __restrict__ A,
    const float* __restrict__ Bm, const float* __restrict__ lam_p,
    const float* __restrict__ W, const float* __restrict__ bvec,
    float* __restrict__ out)
{
  __shared__ __align__(16) float xs[CIN][28];
  __shared__ __align__(16) float Ms[KNUM][VV][28];   // [k][v][w] padded
  const int nt = blockIdx.x;
  const int n = nt >> 6, t = nt & 63;
  const int tid = threadIdx.x;
  const float lam = lam_p[0];

  const float* xp = x + (((long)(n * CIN + tid) * TDIM + t) * VV);
  #pragma unroll
  for (int v = 0; v < VV; ++v) xs[tid][v] = xp[v];
  xs[tid][25] = xs[tid][26] = xs[tid][27] = 0.f;
  for (int i = tid; i < KNUM * VV * VV; i += 256) {
    int k = i / (VV * VV);
    int r = i - k * VV * VV;
    int v = r / VV;
    int w = r - v * VV;
    Ms[k][v][w] = (k < ET) ? A[(k * VV + v) * VV + w]
                           : lam * Bm[(((n * ET) + (k - ET)) * VV + v) * VV + w];
    if (w == 24) { Ms[k][v][25] = Ms[k][v][26] = Ms[k][v][27] = 0.f; }
  }
  __syncthreads();

  float oacc[28] = {};
  for (int k = 0; k < KNUM; ++k) {
    float yv[28];
    float bv = bvec[(k << 8) + tid];
    #pragma unroll
    for (int v = 0; v < 28; ++v) yv[v] = 0.f;
    for (int ci = 0; ci < CIN; ++ci) {
      float wl = W[ci * KD + (k << 8) + tid];
      const f32x4* x4 = (const f32x4*)&xs[ci][0];
      #pragma unroll
      for (int q = 0; q < 7; ++q) {
        f32x4 xv = x4[q];
        yv[q*4+0] += wl*xv[0]; yv[q*4+1] += wl*xv[1];
        yv[q*4+2] += wl*xv[2]; yv[q*4+3] += wl*xv[3];
      }
    }
    #pragma unroll
    for (int v = 0; v < VV; ++v) {
      float yvv = yv[v] + bv;
      const f32x4* m4 = (const f32x4*)&Ms[k][v][0];
      #pragma unroll
      for (int q = 0; q < 7; ++q) {
        f32x4 mv = m4[q];
        oacc[q*4+0] += yvv*mv[0]; oacc[q*4+1] += yvv*mv[1];
        oacc[q*4+2] += yvv*mv[2]; oacc[q*4+3] += yvv*mv[3];
      }
    }
  }
  float* op = out + (((long)(n * COUT + tid) * TDIM + t) * VV);
  #pragma unroll
  for (int w = 0; w < VV; ++w) op[w] = oacc[w];
}

__global__ void copyA_kernel(const float* __restrict__ A, float* __restrict__ outA) {
  int i = blockIdx.x * 256 + threadIdx.x;
  if (i < ACNT) outA[i] = A[i];
}

extern "C" void kernel_launch(void* const* d_in, const int* in_sizes, int n_in,
                              void* d_out, int out_size, void* d_ws, size_t ws_size,
                              hipStream_t stream) {
  const float* x   = (const float*)d_in[0];
  const float* A   = (const float*)d_in[1];
  const float* Bm  = (const float*)d_in[2];
  const float* lam = (const float*)d_in[3];
  const float* W   = (const float*)d_in[4];
  const float* bv  = (const float*)d_in[5];
  float* out = (float*)d_out;

  if (d_ws != nullptr && ws_size >= WS_NEED) {
    bf16_t* wp3     = (bf16_t*)d_ws;
    float*  biasmat = (float*)((char*)d_ws + BIAS_OFF);
    constexpr int PREP_ITEMS = WP3_CHUNKS + NB * VV * COUT + ACNT;
    prep_kernel<<<(PREP_ITEMS + 255) / 256, 256, 0, stream>>>(A, Bm, lam, W, bv, wp3, biasmat, out + OUT0);
    fused_kernel<<<NB * 16, 512, 0, stream>>>(x, A, Bm, lam, wp3, biasmat, out);
  } else {
    fallback_kernel<<<NB * TDIM, 256, 0, stream>>>(x, A, Bm, lam, W, bv, out);
    copyA_kernel<<<(ACNT + 255) / 256, 256, 0, stream>>>(A, out + OUT0);
  }
}

// Round 17
// 76.633 us; speedup vs baseline: 1.1126x; 1.1126x over previous
//
#include <hip/hip_runtime.h>
#include <hip/hip_bf16.h>
#include <stdint.h>

typedef __bf16 bf16_t;
typedef bf16_t bf16x8 __attribute__((ext_vector_type(8)));
typedef float f32x4 __attribute__((ext_vector_type(4)));

#define DEVI static __device__ __forceinline__

constexpr int NB = 32, CIN = 256, COUT = 256, KNUM = 6, ET = 3, TDIM = 64, VV = 25;
constexpr int KD   = KNUM * CIN;       // 1536 contraction dim (k,ci)
constexpr long OUT0 = (long)NB * COUT * TDIM * VV;  // 13107200 (x_sum elems)
constexpr int ACNT = ET * VV * VV;     // 1875 (A copy)

// wp3: W in fragment-order. 24 steps x 2048 chunks x 16B = 768 KB. (R7 layout)
constexpr int NSTEP = 24;              // 4 cb x 6 k
constexpr int WP3_CHUNKS = NSTEP * 2048;
constexpr size_t WP3_BYTES  = (size_t)WP3_CHUNKS * 16;      // 768 KB
constexpr size_t BIAS_OFF   = WP3_BYTES;
constexpr size_t BIAS_BYTES = (size_t)NB * VV * COUT * 4;   // bias [n][w][c] f32
constexpr size_t WS_NEED    = BIAS_OFF + BIAS_BYTES;

DEVI unsigned packbf(float lo, float hi) {
  unsigned short a = __builtin_bit_cast(unsigned short, (bf16_t)lo);
  unsigned short b = __builtin_bit_cast(unsigned short, (bf16_t)hi);
  return ((unsigned)b << 16) | (unsigned)a;
}

// ---------------- prep: wp3 fragment-layout + bias table + A copy ----------
__global__ __launch_bounds__(256) void prep_kernel(
    const float* __restrict__ A, const float* __restrict__ Bm,
    const float* __restrict__ lam_p, const float* __restrict__ W,
    const float* __restrict__ bvec, bf16_t* __restrict__ wp3,
    float* __restrict__ biasmat, float* __restrict__ outA)
{
  int idx = blockIdx.x * 256 + threadIdx.x;
  constexpr int S1 = WP3_CHUNKS;            // 49152 (one 16B chunk per thread)
  constexpr int S2 = S1 + NB * VV * COUT;   // +204800
  constexpr int S3 = S2 + ACNT;
  if (idx < S1) {
    int s  = idx >> 11;
    int r  = idx & 2047;
    int mi = r >> 7;
    int kk = (r >> 6) & 1;
    int ln = r & 63;
    int lg = ln >> 4, lw = ln & 15;
    int cb = s / 6, k = s - cb * 6;
    int cibase = cb * 64 + (lg + 4 * kk) * 8;
    int col = (k << 8) + mi * 16 + lw;
    bf16_t* dst = wp3 + ((long)idx << 3);
    #pragma unroll
    for (int e = 0; e < 8; ++e)
      dst[e] = (bf16_t)W[(cibase + e) * KD + col];
  } else if (idx < S2) {
    // bias[n][w][c] = sum_k b[k*256+c] * S[n,k,w],  S = col-sum of M (lam folded)
    int j = idx - S1;
    int c = j & 255;
    int nw = j >> 8;
    int w = nw % VV;
    int n = nw / VV;
    float lam = lam_p[0];
    float s = 0.f;
    for (int k = 0; k < KNUM; ++k) {
      float sk = 0.f;
      if (k < ET) {
        for (int v = 0; v < VV; ++v) sk += A[(k * VV + v) * VV + w];
      } else {
        for (int v = 0; v < VV; ++v) sk += Bm[(((n * ET) + (k - ET)) * VV + v) * VV + w];
        sk *= lam;
      }
      s += bvec[(k << 8) + c] * sk;
    }
    biasmat[j] = s;
  } else if (idx < S3) {
    int j = idx - S2;
    outA[j] = A[j];   // second tuple output: A passthrough
  }
}

// ---------------- fused kernel (R15 minus redundant end-of-step barrier) -----
// Per step (cb,k): af2a <- wp3 at step top (completes under #1 - T14); MFMA#1
// Xs x Ms -> Bs[buf] (XOR-swz, dbuf); ONE barrier; MFMA#2 kk=0 (prefetched)
// then kk=1 (frags at use). End-of-step barrier REMOVED: with dbuf, reads of
// buf(s) precede bar(s+1) in program order and write(s+2) follows it - safe.
// Waves may drift across phases => wave-level overlap (m114).
__global__ __launch_bounds__(512, 4) void fused_kernel(
    const float* __restrict__ x, const float* __restrict__ A,
    const float* __restrict__ Bm, const float* __restrict__ lam_p,
    const bf16_t* __restrict__ wp3, const float* __restrict__ biasmat,
    float* __restrict__ out)
{
  __shared__ __align__(16) bf16_t Bs[2 * 128 * 64];  // 32 KB dbuf, rows 128B, XOR-swz
  __shared__ __align__(16) bf16_t Xs[256 * 32];      // 16 KB [row=dt*64+ci][v] swizzled
  __shared__ __align__(16) bf16_t Ms[KNUM * 32 * 32];// 12 KB [k][w][v] swizzled, zero-pad

  const int b = blockIdx.x;
  const int n = b >> 4;                  // 0..31
  const int t0 = (b & 15) << 2;          // t-group of 4
  const int tid = threadIdx.x;
  const int wv = tid >> 6, ln = tid & 63;
  const int lw = ln & 15, lg = ln >> 4;
  const float lam = lam_p[0];

  // stage Ms once: row R=k*32+w (64B), group-XOR sw2=(w&3)^((w>>2)&3)
  for (int i = tid; i < KNUM * 32 * 32; i += 512) {
    int R = i >> 5, v = i & 31;
    int k = i >> 10, w = (i >> 5) & 31;
    float val = 0.f;
    if (w < VV && v < VV)
      val = (k < ET) ? A[(k * VV + v) * VV + w]
                     : lam * Bm[(((n * ET) + (k - ET)) * VV + v) * VV + w];
    int sw2 = (w & 3) ^ ((w >> 2) & 3);
    int byteoff = R * 64 + ((((v >> 3) ^ sw2) & 3) << 4) + ((v & 7) << 1);
    *(bf16_t*)((char*)Ms + byteoff) = (bf16_t)val;
  }

  f32x4 acc[4][4] = {};
  const int m_base = (wv >> 1) * 64;
  const int mb4 = (wv >> 1) * 4;         // mi base for A-fragments
  const int n_base = (wv & 1) * 64;
  const f32x4 z4 = {0.f, 0.f, 0.f, 0.f};
  const int msw2 = (lw & 3) ^ ((lw >> 2) & 3);   // Ms read swizzle

  #pragma unroll 1
  for (int cb = 0; cb < 4; ++cb) {
    __syncthreads();   // rendezvous: all waves past their last Xs reads of prev cb
    // stage Xs (R7 verbatim): rows dt*64+ci, group-XOR swizzle
    if (tid < 256) {
      int ci = tid >> 2, dt = tid & 3;
      const float* xp = x + ((long)(n * CIN + cb * 64 + ci) * TDIM + t0 + dt) * VV;
      float xv[25];
      #pragma unroll
      for (int v = 0; v < VV; ++v) xv[v] = xp[v];
      int row = dt * 64 + ci;
      int sw = (row & 3) ^ ((row >> 2) & 3);
      #pragma unroll
      for (int g = 0; g < 4; ++g) {
        char* base = (char*)Xs + row * 64 + ((g ^ sw) & 3) * 16;
        #pragma unroll
        for (int p = 0; p < 4; ++p) {
          int v0 = g * 8 + p * 2;
          float lo = (v0     < VV) ? xv[v0 < VV ? v0 : 0]     : 0.f;
          float hi = (v0 + 1 < VV) ? xv[v0 + 1 < VV ? v0 + 1 : 0] : 0.f;
          *(unsigned*)(base + p * 4) = packbf(lo, hi);
        }
      }
    }
    __syncthreads();   // Xs visible

    #pragma unroll 1
    for (int k = 0; k < KNUM; ++k) {
      const int s = cb * 6 + k;
      const int buf = (s & 1) * (128 * 64);
      const bf16_t* wpS = wp3 + (((long)s * 2048 + (long)mb4 * 128 + ln) << 3);

      // A fragments kk=0: issued early, complete under #1 (T14 issue-early)
      bf16x8 af2a[4];
      #pragma unroll
      for (int i = 0; i < 4; ++i)
        af2a[i] = *(const bf16x8*)(wpS + ((i * 128) << 3));

      // MFMA#1: Xs x Ms -> Bs[buf]
      bf16x8 mb0 = *(const bf16x8*)((const char*)Ms + (k * 32 + lw) * 64 + (((lg ^ msw2) & 3) << 4));
      bf16x8 mb1 = *(const bf16x8*)((const char*)Ms + (k * 32 + 16 + lw) * 64 + (((lg ^ msw2) & 3) << 4));
      #pragma unroll
      for (int rt = 0; rt < 2; ++rt) {
        int arow = wv * 32 + rt * 16 + lw;
        int sw = (arow & 3) ^ ((arow >> 2) & 3);
        int off = ((lg ^ sw) & 3) << 4;
        bf16x8 af = *(const bf16x8*)((const char*)Xs + arow * 64 + off);
        f32x4 d0 = __builtin_amdgcn_mfma_f32_16x16x32_bf16(af, mb0, z4, 0, 0, 0);
        f32x4 d1 = __builtin_amdgcn_mfma_f32_16x16x32_bf16(af, mb1, z4, 0, 0, 0);
        int rbase = wv * 32 + rt * 16 + (lg << 2);
        int dt = rbase >> 6, ci0 = rbase & 63;
        int r0 = dt * 32 + lw;
        int g0 = ((ci0 >> 3) ^ (r0 & 7)) & 7;
        char* c0 = (char*)(Bs + buf) + r0 * 128 + (g0 << 4) + ((ci0 << 1) & 15);
        *(unsigned*)(c0)     = packbf(d0[0], d0[1]);
        *(unsigned*)(c0 + 4) = packbf(d0[2], d0[3]);
        char* c1 = (char*)(Bs + buf) + (r0 + 16) * 128 + (g0 << 4) + ((ci0 << 1) & 15);
        *(unsigned*)(c1)     = packbf(d1[0], d1[1]);
        *(unsigned*)(c1 + 4) = packbf(d1[2], d1[3]);
      }
      __syncthreads();   // Bs[buf] ready (the ONLY barrier per step; dbuf covers rest)

      // MFMA#2 kk=0 (prefetched A-frags)
      __builtin_amdgcn_s_setprio(1);
      {
        bf16x8 bf2[4];
        #pragma unroll
        for (int j = 0; j < 4; ++j) {
          int rr = n_base + j * 16 + lw;
          int gg = (lg ^ (rr & 7)) & 7;
          bf2[j] = *(const bf16x8*)((const char*)(Bs + buf) + rr * 128 + (gg << 4));
        }
        #pragma unroll
        for (int i = 0; i < 4; ++i)
          #pragma unroll
          for (int j = 0; j < 4; ++j)
            acc[i][j] = __builtin_amdgcn_mfma_f32_16x16x32_bf16(af2a[i], bf2[j], acc[i][j], 0, 0, 0);
      }
      // MFMA#2 kk=1 (A-frags loaded at use; TLP covers the L2 latency)
      {
        bf16x8 af2b[4];
        #pragma unroll
        for (int i = 0; i < 4; ++i)
          af2b[i] = *(const bf16x8*)(wpS + ((i * 128 + 64) << 3));
        bf16x8 bf2[4];
        #pragma unroll
        for (int j = 0; j < 4; ++j) {
          int rr = n_base + j * 16 + lw;
          int gg = ((4 + lg) ^ (rr & 7)) & 7;
          bf2[j] = *(const bf16x8*)((const char*)(Bs + buf) + rr * 128 + (gg << 4));
        }
        #pragma unroll
        for (int i = 0; i < 4; ++i)
          #pragma unroll
          for (int j = 0; j < 4; ++j)
            acc[i][j] = __builtin_amdgcn_mfma_f32_16x16x32_bf16(af2b[i], bf2[j], acc[i][j], 0, 0, 0);
      }
      __builtin_amdgcn_s_setprio(0);
      // (end-of-step barrier removed: dbuf invariant proves safety)
    }
  }

  // epilogue: C/D map col=lane&15, row=(lane>>4)*4+reg [m89-verified]
  #pragma unroll
  for (int j = 0; j < 4; ++j) {
    int colb = n_base + j * 16 + lw;         // 0..127
    int dt = colb >> 5, w = colb & 31;
    if (w < VV) {
      float* ob = out + (long)n * 409600 + (t0 + dt) * 25 + w;
      const float* brow = biasmat + (n * 25 + w) * 256;
      #pragma unroll
      for (int i = 0; i < 4; ++i) {
        int mb = m_base + i * 16 + (lg << 2);
        #pragma unroll
        for (int r = 0; r < 4; ++r) {
          int m = mb + r;
          ob[(long)m * 1600] = acc[i][j][r] + brow[m];
        }
      }
    }
  }
}

// ---------------- ws-free fp32 fallback (insurance) ----------------
__global__ __launch_bounds__(256) void fallback_kernel(
    const float* __restrict__ x, const float* __restrict__ A,
    const float* __restrict__ Bm, const float* __restrict__ lam_p,
    const float* __restrict__ W, const float* __restrict__ bvec,
    float* __restrict__ out)
{
  __shared__ __align__(16) float xs[CIN][28];
  __shared__ __align__(16) float Ms[KNUM][VV][28];   // [k][v][w] padded
  const int nt = blockIdx.x;
  const int n = nt >> 6, t = nt & 63;
  const int tid = threadIdx.x;
  const float lam = lam_p[0];

  const float* xp = x + (((long)(n * CIN + tid) * TDIM + t) * VV);
  #pragma unroll
  for (int v = 0; v < VV; ++v) xs[tid][v] = xp[v];
  xs[tid][25] = xs[tid][26] = xs[tid][27] = 0.f;
  for (int i = tid; i < KNUM * VV * VV; i += 256) {
    int k = i / (VV * VV);
    int r = i - k * VV * VV;
    int v = r / VV;
    int w = r - v * VV;
    Ms[k][v][w] = (k < ET) ? A[(k * VV + v) * VV + w]
                           : lam * Bm[(((n * ET) + (k - ET)) * VV + v) * VV + w];
    if (w == 24) { Ms[k][v][25] = Ms[k][v][26] = Ms[k][v][27] = 0.f; }
  }
  __syncthreads();

  float oacc[28] = {};
  for (int k = 0; k < KNUM; ++k) {
    float yv[28];
    float bv = bvec[(k << 8) + tid];
    #pragma unroll
    for (int v = 0; v < 28; ++v) yv[v] = 0.f;
    for (int ci = 0; ci < CIN; ++ci) {
      float wl = W[ci * KD + (k << 8) + tid];
      const f32x4* x4 = (const f32x4*)&xs[ci][0];
      #pragma unroll
      for (int q = 0; q < 7; ++q) {
        f32x4 xv = x4[q];
        yv[q*4+0] += wl*xv[0]; yv[q*4+1] += wl*xv[1];
        yv[q*4+2] += wl*xv[2]; yv[q*4+3] += wl*xv[3];
      }
    }
    #pragma unroll
    for (int v = 0; v < VV; ++v) {
      float yvv = yv[v] + bv;
      const f32x4* m4 = (const f32x4*)&Ms[k][v][0];
      #pragma unroll
      for (int q = 0; q < 7; ++q) {
        f32x4 mv = m4[q];
        oacc[q*4+0] += yvv*mv[0]; oacc[q*4+1] += yvv*mv[1];
        oacc[q*4+2] += yvv*mv[2]; oacc[q*4+3] += yvv*mv[3];
      }
    }
  }
  float* op = out + (((long)(n * COUT + tid) * TDIM + t) * VV);
  #pragma unroll
  for (int w = 0; w < VV; ++w) op[w] = oacc[w];
}

__global__ void copyA_kernel(const float* __restrict__ A, float* __restrict__ outA) {
  int i = blockIdx.x * 256 + threadIdx.x;
  if (i < ACNT) outA[i] = A[i];
}

extern "C" void kernel_launch(void* const* d_in, const int* in_sizes, int n_in,
                              void* d_out, int out_size, void* d_ws, size_t ws_size,
                              hipStream_t stream) {
  const float* x   = (const float*)d_in[0];
  const float* A   = (const float*)d_in[1];
  const float* Bm  = (const float*)d_in[2];
  const float* lam = (const float*)d_in[3];
  const float* W   = (const float*)d_in[4];
  const float* bv  = (const float*)d_in[5];
  float* out = (float*)d_out;

  if (d_ws != nullptr && ws_size >= WS_NEED) {
    bf16_t* wp3     = (bf16_t*)d_ws;
    float*  biasmat = (float*)((char*)d_ws + BIAS_OFF);
    constexpr int PREP_ITEMS = WP3_CHUNKS + NB * VV * COUT + ACNT;
    prep_kernel<<<(PREP_ITEMS + 255) / 256, 256, 0, stream>>>(A, Bm, lam, W, bv, wp3, biasmat, out + OUT0);
    fused_kernel<<<NB * 16, 512, 0, stream>>>(x, A, Bm, lam, wp3, biasmat, out);
  } else {
    fallback_kernel<<<NB * TDIM, 256, 0, stream>>>(x, A, Bm, lam, W, bv, out);
    copyA_kernel<<<(ACNT + 255) / 256, 256, 0, stream>>>(A, out + OUT0);
  }
}

// Round 18
// 74.021 us; speedup vs baseline: 1.1519x; 1.0353x over previous
//
#include <hip/hip_runtime.h>
#include <hip/hip_bf16.h>
#include <stdint.h>

typedef __bf16 bf16_t;
typedef bf16_t bf16x8 __attribute__((ext_vector_type(8)));
typedef float f32x4 __attribute__((ext_vector_type(4)));

#define DEVI static __device__ __forceinline__

constexpr int NB = 32, CIN = 256, COUT = 256, KNUM = 6, ET = 3, TDIM = 64, VV = 25;
constexpr int KD   = KNUM * CIN;       // 1536 contraction dim (k,ci)
constexpr long OUT0 = (long)NB * COUT * TDIM * VV;  // 13107200 (x_sum elems)
constexpr int ACNT = ET * VV * VV;     // 1875 (A copy)

// wp3: W in fragment-order. 24 steps x 2048 chunks x 16B = 768 KB. (R7 layout)
constexpr int NSTEP = 24;              // 4 cb x 6 k
constexpr int WP3_CHUNKS = NSTEP * 2048;
constexpr size_t WP3_BYTES  = (size_t)WP3_CHUNKS * 16;      // 768 KB
constexpr size_t BIAS_OFF   = WP3_BYTES;
constexpr size_t BIAS_BYTES = (size_t)NB * VV * COUT * 4;   // bias [n][w][c] f32
constexpr size_t WS_NEED    = BIAS_OFF + BIAS_BYTES;

DEVI unsigned packbf(float lo, float hi) {
  unsigned short a = __builtin_bit_cast(unsigned short, (bf16_t)lo);
  unsigned short b = __builtin_bit_cast(unsigned short, (bf16_t)hi);
  return ((unsigned)b << 16) | (unsigned)a;
}

// ---------------- prep: wp3 fragment-layout + bias table + A copy ----------
__global__ __launch_bounds__(256) void prep_kernel(
    const float* __restrict__ A, const float* __restrict__ Bm,
    const float* __restrict__ lam_p, const float* __restrict__ W,
    const float* __restrict__ bvec, bf16_t* __restrict__ wp3,
    float* __restrict__ biasmat, float* __restrict__ outA)
{
  int idx = blockIdx.x * 256 + threadIdx.x;
  constexpr int S1 = WP3_CHUNKS;            // 49152 (one 16B chunk per thread)
  constexpr int S2 = S1 + NB * VV * COUT;   // +204800
  constexpr int S3 = S2 + ACNT;
  if (idx < S1) {
    int s  = idx >> 11;
    int r  = idx & 2047;
    int mi = r >> 7;
    int kk = (r >> 6) & 1;
    int ln = r & 63;
    int lg = ln >> 4, lw = ln & 15;
    int cb = s / 6, k = s - cb * 6;
    int cibase = cb * 64 + (lg + 4 * kk) * 8;
    int col = (k << 8) + mi * 16 + lw;
    bf16_t* dst = wp3 + ((long)idx << 3);
    #pragma unroll
    for (int e = 0; e < 8; ++e)
      dst[e] = (bf16_t)W[(cibase + e) * KD + col];
  } else if (idx < S2) {
    // bias[n][w][c] = sum_k b[k*256+c] * S[n,k,w],  S = col-sum of M (lam folded)
    int j = idx - S1;
    int c = j & 255;
    int nw = j >> 8;
    int w = nw % VV;
    int n = nw / VV;
    float lam = lam_p[0];
    float s = 0.f;
    for (int k = 0; k < KNUM; ++k) {
      float sk = 0.f;
      if (k < ET) {
        for (int v = 0; v < VV; ++v) sk += A[(k * VV + v) * VV + w];
      } else {
        for (int v = 0; v < VV; ++v) sk += Bm[(((n * ET) + (k - ET)) * VV + v) * VV + w];
        sk *= lam;
      }
      s += bvec[(k << 8) + c] * sk;
    }
    biasmat[j] = s;
  } else if (idx < S3) {
    int j = idx - S2;
    outA[j] = A[j];   // second tuple output: A passthrough
  }
}

// ---------------- fused kernel (R17 + 80B-row pad + bounce epilogue) ---------
// Per step (cb,k): af2a <- wp3 at step top (completes under #1); MFMA#1
// Xs x Ms -> Bs[buf] (dbuf); ONE barrier; MFMA#2 kk=0 then kk=1.
// Xs/Ms rows padded 64->80B: row bank-offset (r*20)%32 spreads 8 offsets,
// killing the 8-way read conflicts (was 10 extra cyc per read, measured).
// Epilogue: LDS-bounce through Bs for dense 400B-contiguous out writes.
__global__ __launch_bounds__(512, 4) void fused_kernel(
    const float* __restrict__ x, const float* __restrict__ A,
    const float* __restrict__ Bm, const float* __restrict__ lam_p,
    const bf16_t* __restrict__ wp3, const float* __restrict__ biasmat,
    float* __restrict__ out)
{
  __shared__ __align__(16) bf16_t Bs[2 * 128 * 64];  // 32 KB dbuf (epilogue: eb)
  __shared__ __align__(16) bf16_t Xs[256 * 40];      // 20 KB, 80B rows
  __shared__ __align__(16) bf16_t Ms[KNUM * 32 * 40];// 15 KB, 80B rows

  const int b = blockIdx.x;
  const int n = b >> 4;                  // 0..31
  const int t0 = (b & 15) << 2;          // t-group of 4
  const int tid = threadIdx.x;
  const int wv = tid >> 6, ln = tid & 63;
  const int lw = ln & 15, lg = ln >> 4;
  const float lam = lam_p[0];

  // stage Ms once: row R=k*32+w (80B), group-XOR sw2=(w&3)^((w>>2)&3)
  for (int i = tid; i < KNUM * 32 * 32; i += 512) {
    int R = i >> 5, v = i & 31;
    int k = i >> 10, w = (i >> 5) & 31;
    float val = 0.f;
    if (w < VV && v < VV)
      val = (k < ET) ? A[(k * VV + v) * VV + w]
                     : lam * Bm[(((n * ET) + (k - ET)) * VV + v) * VV + w];
    int sw2 = (w & 3) ^ ((w >> 2) & 3);
    int byteoff = R * 80 + ((((v >> 3) ^ sw2) & 3) << 4) + ((v & 7) << 1);
    *(bf16_t*)((char*)Ms + byteoff) = (bf16_t)val;
  }

  f32x4 acc[4][4] = {};
  const int m_base = (wv >> 1) * 64;
  const int mb4 = (wv >> 1) * 4;         // mi base for A-fragments
  const int n_base = (wv & 1) * 64;
  const f32x4 z4 = {0.f, 0.f, 0.f, 0.f};
  const int msw2 = (lw & 3) ^ ((lw >> 2) & 3);   // Ms read swizzle

  #pragma unroll 1
  for (int cb = 0; cb < 4; ++cb) {
    __syncthreads();   // rendezvous: all waves past their last Xs reads of prev cb
    // stage Xs: rows dt*64+ci (80B rows), group-XOR swizzle
    if (tid < 256) {
      int ci = tid >> 2, dt = tid & 3;
      const float* xp = x + ((long)(n * CIN + cb * 64 + ci) * TDIM + t0 + dt) * VV;
      float xv[25];
      #pragma unroll
      for (int v = 0; v < VV; ++v) xv[v] = xp[v];
      int row = dt * 64 + ci;
      int sw = (row & 3) ^ ((row >> 2) & 3);
      #pragma unroll
      for (int g = 0; g < 4; ++g) {
        char* base = (char*)Xs + row * 80 + ((g ^ sw) & 3) * 16;
        #pragma unroll
        for (int p = 0; p < 4; ++p) {
          int v0 = g * 8 + p * 2;
          float lo = (v0     < VV) ? xv[v0 < VV ? v0 : 0]     : 0.f;
          float hi = (v0 + 1 < VV) ? xv[v0 + 1 < VV ? v0 + 1 : 0] : 0.f;
          *(unsigned*)(base + p * 4) = packbf(lo, hi);
        }
      }
    }
    __syncthreads();   // Xs visible

    #pragma unroll 1
    for (int k = 0; k < KNUM; ++k) {
      const int s = cb * 6 + k;
      const int buf = (s & 1) * (128 * 64);
      const bf16_t* wpS = wp3 + (((long)s * 2048 + (long)mb4 * 128 + ln) << 3);

      // A fragments kk=0: issued early, complete under #1 (T14 issue-early)
      bf16x8 af2a[4];
      #pragma unroll
      for (int i = 0; i < 4; ++i)
        af2a[i] = *(const bf16x8*)(wpS + ((i * 128) << 3));

      // MFMA#1: Xs x Ms -> Bs[buf]
      bf16x8 mb0 = *(const bf16x8*)((const char*)Ms + (k * 32 + lw) * 80 + (((lg ^ msw2) & 3) << 4));
      bf16x8 mb1 = *(const bf16x8*)((const char*)Ms + (k * 32 + 16 + lw) * 80 + (((lg ^ msw2) & 3) << 4));
      #pragma unroll
      for (int rt = 0; rt < 2; ++rt) {
        int arow = wv * 32 + rt * 16 + lw;
        int sw = (arow & 3) ^ ((arow >> 2) & 3);
        int off = ((lg ^ sw) & 3) << 4;
        bf16x8 af = *(const bf16x8*)((const char*)Xs + arow * 80 + off);
        f32x4 d0 = __builtin_amdgcn_mfma_f32_16x16x32_bf16(af, mb0, z4, 0, 0, 0);
        f32x4 d1 = __builtin_amdgcn_mfma_f32_16x16x32_bf16(af, mb1, z4, 0, 0, 0);
        int rbase = wv * 32 + rt * 16 + (lg << 2);
        int dt = rbase >> 6, ci0 = rbase & 63;
        int r0 = dt * 32 + lw;
        int g0 = ((ci0 >> 3) ^ (r0 & 7)) & 7;
        char* c0 = (char*)(Bs + buf) + r0 * 128 + (g0 << 4) + ((ci0 << 1) & 15);
        *(unsigned*)(c0)     = packbf(d0[0], d0[1]);
        *(unsigned*)(c0 + 4) = packbf(d0[2], d0[3]);
        char* c1 = (char*)(Bs + buf) + (r0 + 16) * 128 + (g0 << 4) + ((ci0 << 1) & 15);
        *(unsigned*)(c1)     = packbf(d1[0], d1[1]);
        *(unsigned*)(c1 + 4) = packbf(d1[2], d1[3]);
      }
      __syncthreads();   // Bs[buf] ready (the ONLY barrier per step; dbuf covers rest)

      // MFMA#2 kk=0 (prefetched A-frags)
      __builtin_amdgcn_s_setprio(1);
      {
        bf16x8 bf2[4];
        #pragma unroll
        for (int j = 0; j < 4; ++j) {
          int rr = n_base + j * 16 + lw;
          int gg = (lg ^ (rr & 7)) & 7;
          bf2[j] = *(const bf16x8*)((const char*)(Bs + buf) + rr * 128 + (gg << 4));
        }
        #pragma unroll
        for (int i = 0; i < 4; ++i)
          #pragma unroll
          for (int j = 0; j < 4; ++j)
            acc[i][j] = __builtin_amdgcn_mfma_f32_16x16x32_bf16(af2a[i], bf2[j], acc[i][j], 0, 0, 0);
      }
      // MFMA#2 kk=1 (A-frags loaded at use; TLP covers the L2 latency)
      {
        bf16x8 af2b[4];
        #pragma unroll
        for (int i = 0; i < 4; ++i)
          af2b[i] = *(const bf16x8*)(wpS + ((i * 128 + 64) << 3));
        bf16x8 bf2[4];
        #pragma unroll
        for (int j = 0; j < 4; ++j) {
          int rr = n_base + j * 16 + lw;
          int gg = ((4 + lg) ^ (rr & 7)) & 7;
          bf2[j] = *(const bf16x8*)((const char*)(Bs + buf) + rr * 128 + (gg << 4));
        }
        #pragma unroll
        for (int i = 0; i < 4; ++i)
          #pragma unroll
          for (int j = 0; j < 4; ++j)
            acc[i][j] = __builtin_amdgcn_mfma_f32_16x16x32_bf16(af2b[i], bf2[j], acc[i][j], 0, 0, 0);
      }
      __builtin_amdgcn_s_setprio(0);
      // (no end-of-step barrier: dbuf invariant proves safety)
    }
  }

  // ---- epilogue: LDS-bounce dense writes (bias folded at eb-write) ----------
  // Round rnd: waves (wv>>1)==rnd write their 64 c-rows (cl=0..63) into
  // eb[cl][100] = [dt*25+w]; then all 512 threads stream 1600 float4s out.
  // eb read addr = 16*idx (linear, conflict-free); out rows 400B contiguous.
  __syncthreads();   // all #2 reads of Bs complete
  float* eb = (float*)Bs;   // 64 x 100 f32 = 25.6 KB
  #pragma unroll 1
  for (int rnd = 0; rnd < 4; ++rnd) {
    if ((wv >> 1) == rnd) {
      #pragma unroll
      for (int j = 0; j < 4; ++j) {
        int col = n_base + j * 16 + lw;
        int dt = col >> 5, w = col & 31;
        if (w < VV) {
          const float* brow = biasmat + (n * 25 + w) * 256 + rnd * 64;
          #pragma unroll
          for (int i = 0; i < 4; ++i) {
            #pragma unroll
            for (int r = 0; r < 4; ++r) {
              int cl = i * 16 + (lg << 2) + r;
              eb[cl * 100 + dt * 25 + w] = acc[i][j][r] + brow[cl];
            }
          }
        }
      }
    }
    __syncthreads();
    #pragma unroll
    for (int it = 0; it < 4; ++it) {
      int idx = it * 512 + tid;
      if (idx < 1600) {
        int cl = idx / 25, f4 = idx - cl * 25;
        f32x4 val = *(const f32x4*)(eb + cl * 100 + f4 * 4);
        *(f32x4*)(out + (long)n * 409600 + (long)(rnd * 64 + cl) * 1600
                      + t0 * 25 + f4 * 4) = val;
      }
    }
    __syncthreads();   // eb free for next round
  }
}

// ---------------- ws-free fp32 fallback (insurance) ----------------
__global__ __launch_bounds__(256) void fallback_kernel(
    const float* __restrict__ x, const float* __restrict__ A,
    const float* __restrict__ Bm, const float* __restrict__ lam_p,
    const float* __restrict__ W, const float* __restrict__ bvec,
    float* __restrict__ out)
{
  __shared__ __align__(16) float xs[CIN][28];
  __shared__ __align__(16) float Ms[KNUM][VV][28];   // [k][v][w] padded
  const int nt = blockIdx.x;
  const int n = nt >> 6, t = nt & 63;
  const int tid = threadIdx.x;
  const float lam = lam_p[0];

  const float* xp = x + (((long)(n * CIN + tid) * TDIM + t) * VV);
  #pragma unroll
  for (int v = 0; v < VV; ++v) xs[tid][v] = xp[v];
  xs[tid][25] = xs[tid][26] = xs[tid][27] = 0.f;
  for (int i = tid; i < KNUM * VV * VV; i += 256) {
    int k = i / (VV * VV);
    int r = i - k * VV * VV;
    int v = r / VV;
    int w = r - v * VV;
    Ms[k][v][w] = (k < ET) ? A[(k * VV + v) * VV + w]
                           : lam * Bm[(((n * ET) + (k - ET)) * VV + v) * VV + w];
    if (w == 24) { Ms[k][v][25] = Ms[k][v][26] = Ms[k][v][27] = 0.f; }
  }
  __syncthreads();

  float oacc[28] = {};
  for (int k = 0; k < KNUM; ++k) {
    float yv[28];
    float bv = bvec[(k << 8) + tid];
    #pragma unroll
    for (int v = 0; v < 28; ++v) yv[v] = 0.f;
    for (int ci = 0; ci < CIN; ++ci) {
      float wl = W[ci * KD + (k << 8) + tid];
      const f32x4* x4 = (const f32x4*)&xs[ci][0];
      #pragma unroll
      for (int q = 0; q < 7; ++q) {
        f32x4 xv = x4[q];
        yv[q*4+0] += wl*xv[0]; yv[q*4+1] += wl*xv[1];
        yv[q*4+2] += wl*xv[2]; yv[q*4+3] += wl*xv[3];
      }
    }
    #pragma unroll
    for (int v = 0; v < VV; ++v) {
      float yvv = yv[v] + bv;
      const f32x4* m4 = (const f32x4*)&Ms[k][v][0];
      #pragma unroll
      for (int q = 0; q < 7; ++q) {
        f32x4 mv = m4[q];
        oacc[q*4+0] += yvv*mv[0]; oacc[q*4+1] += yvv*mv[1];
        oacc[q*4+2] += yvv*mv[2]; oacc[q*4+3] += yvv*mv[3];
      }
    }
  }
  float* op = out + (((long)(n * COUT + tid) * TDIM + t) * VV);
  #pragma unroll
  for (int w = 0; w < VV; ++w) op[w] = oacc[w];
}

__global__ void copyA_kernel(const float* __restrict__ A, float* __restrict__ outA) {
  int i = blockIdx.x * 256 + threadIdx.x;
  if (i < ACNT) outA[i] = A[i];
}

extern "C" void kernel_launch(void* const* d_in, const int* in_sizes, int n_in,
                              void* d_out, int out_size, void* d_ws, size_t ws_size,
                              hipStream_t stream) {
  const float* x   = (const float*)d_in[0];
  const float* A   = (const float*)d_in[1];
  const float* Bm  = (const float*)d_in[2];
  const float* lam = (const float*)d_in[3];
  const float* W   = (const float*)d_in[4];
  const float* bv  = (const float*)d_in[5];
  float* out = (float*)d_out;

  if (d_ws != nullptr && ws_size >= WS_NEED) {
    bf16_t* wp3     = (bf16_t*)d_ws;
    float*  biasmat = (float*)((char*)d_ws + BIAS_OFF);
    constexpr int PREP_ITEMS = WP3_CHUNKS + NB * VV * COUT + ACNT;
    prep_kernel<<<(PREP_ITEMS + 255) / 256, 256, 0, stream>>>(A, Bm, lam, W, bv, wp3, biasmat, out + OUT0);
    fused_kernel<<<NB * 16, 512, 0, stream>>>(x, A, Bm, lam, wp3, biasmat, out);
  } else {
    fallback_kernel<<<NB * TDIM, 256, 0, stream>>>(x, A, Bm, lam, W, bv, out);
    copyA_kernel<<<(ACNT + 255) / 256, 256, 0, stream>>>(A, out + OUT0);
  }
}

// Round 19
// 73.592 us; speedup vs baseline: 1.1586x; 1.0058x over previous
//
#include <hip/hip_runtime.h>
#include <hip/hip_bf16.h>
#include <stdint.h>

typedef __bf16 bf16_t;
typedef bf16_t bf16x8 __attribute__((ext_vector_type(8)));
typedef float f32x4 __attribute__((ext_vector_type(4)));

#define DEVI static __device__ __forceinline__

constexpr int NB = 32, CIN = 256, COUT = 256, KNUM = 6, ET = 3, TDIM = 64, VV = 25;
constexpr int KD   = KNUM * CIN;       // 1536 contraction dim (k,ci)
constexpr long OUT0 = (long)NB * COUT * TDIM * VV;  // 13107200 (x_sum elems)
constexpr int ACNT = ET * VV * VV;     // 1875 (A copy)

// wp3: W in fragment-order. 24 steps x 2048 chunks x 16B = 768 KB. (R7 layout)
constexpr int NSTEP = 24;              // 4 cb x 6 k
constexpr int WP3_CHUNKS = NSTEP * 2048;
constexpr size_t WP3_BYTES  = (size_t)WP3_CHUNKS * 16;      // 768 KB
constexpr size_t BIAS_OFF   = WP3_BYTES;
constexpr size_t BIAS_BYTES = (size_t)NB * VV * COUT * 4;   // bias [n][w][c] f32
constexpr size_t WS_NEED    = BIAS_OFF + BIAS_BYTES;

DEVI unsigned packbf(float lo, float hi) {
  unsigned short a = __builtin_bit_cast(unsigned short, (bf16_t)lo);
  unsigned short b = __builtin_bit_cast(unsigned short, (bf16_t)hi);
  return ((unsigned)b << 16) | (unsigned)a;
}

// ---------------- prep: wp3 fragment-layout + bias table + A copy ----------
__global__ __launch_bounds__(256) void prep_kernel(
    const float* __restrict__ A, const float* __restrict__ Bm,
    const float* __restrict__ lam_p, const float* __restrict__ W,
    const float* __restrict__ bvec, bf16_t* __restrict__ wp3,
    float* __restrict__ biasmat, float* __restrict__ outA)
{
  int idx = blockIdx.x * 256 + threadIdx.x;
  constexpr int S1 = WP3_CHUNKS;            // 49152 (one 16B chunk per thread)
  constexpr int S2 = S1 + NB * VV * COUT;   // +204800
  constexpr int S3 = S2 + ACNT;
  if (idx < S1) {
    int s  = idx >> 11;
    int r  = idx & 2047;
    int mi = r >> 7;
    int kk = (r >> 6) & 1;
    int ln = r & 63;
    int lg = ln >> 4, lw = ln & 15;
    int cb = s / 6, k = s - cb * 6;
    int cibase = cb * 64 + (lg + 4 * kk) * 8;
    int col = (k << 8) + mi * 16 + lw;
    bf16_t* dst = wp3 + ((long)idx << 3);
    #pragma unroll
    for (int e = 0; e < 8; ++e)
      dst[e] = (bf16_t)W[(cibase + e) * KD + col];
  } else if (idx < S2) {
    // bias[n][w][c] = sum_k b[k*256+c] * S[n,k,w],  S = col-sum of M (lam folded)
    int j = idx - S1;
    int c = j & 255;
    int nw = j >> 8;
    int w = nw % VV;
    int n = nw / VV;
    float lam = lam_p[0];
    float s = 0.f;
    for (int k = 0; k < KNUM; ++k) {
      float sk = 0.f;
      if (k < ET) {
        for (int v = 0; v < VV; ++v) sk += A[(k * VV + v) * VV + w];
      } else {
        for (int v = 0; v < VV; ++v) sk += Bm[(((n * ET) + (k - ET)) * VV + v) * VV + w];
        sk *= lam;
      }
      s += bvec[(k << 8) + c] * sk;
    }
    biasmat[j] = s;
  } else if (idx < S3) {
    int j = idx - S2;
    outA[j] = A[j];   // second tuple output: A passthrough
  }
}

// ---------------- fused kernel (R18 minus Xs: x frags direct global->reg) ----
// Per cb, per wave: afx[rt] loaded ONCE from x (each (row,v-group) consumed by
// exactly one lane -> x still read once per block; values identical to the
// old swizzled-LDS round-trip). Per step: af2a <- wp3 (completes under #1);
// MFMA#1 afx x Ms -> Bs[buf] (dbuf); ONE barrier; MFMA#2 kk=0/kk=1.
// LDS = Bs 32K + Ms 15K = 47 KB; no Xs staging, no cb barriers.
__global__ __launch_bounds__(512, 4) void fused_kernel(
    const float* __restrict__ x, const float* __restrict__ A,
    const float* __restrict__ Bm, const float* __restrict__ lam_p,
    const bf16_t* __restrict__ wp3, const float* __restrict__ biasmat,
    float* __restrict__ out)
{
  __shared__ __align__(16) bf16_t Bs[2 * 128 * 64];  // 32 KB dbuf (epilogue: eb)
  __shared__ __align__(16) bf16_t Ms[KNUM * 32 * 40];// 15 KB, 80B rows

  const int b = blockIdx.x;
  const int n = b >> 4;                  // 0..31
  const int t0 = (b & 15) << 2;          // t-group of 4
  const int tid = threadIdx.x;
  const int wv = tid >> 6, ln = tid & 63;
  const int lw = ln & 15, lg = ln >> 4;
  const float lam = lam_p[0];

  // stage Ms once: row R=k*32+w (80B), group-XOR sw2=(w&3)^((w>>2)&3)
  for (int i = tid; i < KNUM * 32 * 32; i += 512) {
    int R = i >> 5, v = i & 31;
    int k = i >> 10, w = (i >> 5) & 31;
    float val = 0.f;
    if (w < VV && v < VV)
      val = (k < ET) ? A[(k * VV + v) * VV + w]
                     : lam * Bm[(((n * ET) + (k - ET)) * VV + v) * VV + w];
    int sw2 = (w & 3) ^ ((w >> 2) & 3);
    int byteoff = R * 80 + ((((v >> 3) ^ sw2) & 3) << 4) + ((v & 7) << 1);
    *(bf16_t*)((char*)Ms + byteoff) = (bf16_t)val;
  }
  __syncthreads();   // Ms visible (once)

  f32x4 acc[4][4] = {};
  const int m_base = (wv >> 1) * 64;
  const int mb4 = (wv >> 1) * 4;         // mi base for A-fragments
  const int n_base = (wv & 1) * 64;
  const int dtw = wv >> 1;               // this wave's dt for #1 rows
  const f32x4 z4 = {0.f, 0.f, 0.f, 0.f};
  const int msw2 = (lw & 3) ^ ((lw >> 2) & 3);   // Ms read swizzle

  #pragma unroll 1
  for (int cb = 0; cb < 4; ++cb) {
    // afx: this wave's x fragments for the whole cb, direct global->VGPR.
    // af values = x[n, cb*64+ci, t0+dtw, lg*8..+7] packed bf16 (v>=25 -> 0).
    bf16x8 afx[2];
    #pragma unroll
    for (int rt = 0; rt < 2; ++rt) {
      int ci = (wv & 1) * 32 + rt * 16 + lw;
      const float* xp = x + ((long)(n * CIN + cb * 64 + ci) * TDIM + t0 + dtw) * VV;
      float xv[8];
      if (lg < 3) {
        #pragma unroll
        for (int e = 0; e < 8; ++e) xv[e] = xp[lg * 8 + e];
      } else {
        xv[0] = xp[24];
        #pragma unroll
        for (int e = 1; e < 8; ++e) xv[e] = 0.f;
      }
      union { unsigned u[4]; bf16x8 v; } u;
      u.u[0] = packbf(xv[0], xv[1]); u.u[1] = packbf(xv[2], xv[3]);
      u.u[2] = packbf(xv[4], xv[5]); u.u[3] = packbf(xv[6], xv[7]);
      afx[rt] = u.v;
    }

    #pragma unroll 1
    for (int k = 0; k < KNUM; ++k) {
      const int s = cb * 6 + k;
      const int buf = (s & 1) * (128 * 64);
      const bf16_t* wpS = wp3 + (((long)s * 2048 + (long)mb4 * 128 + ln) << 3);

      // A fragments kk=0: issued early, complete under #1 (T14 issue-early)
      bf16x8 af2a[4];
      #pragma unroll
      for (int i = 0; i < 4; ++i)
        af2a[i] = *(const bf16x8*)(wpS + ((i * 128) << 3));

      // MFMA#1: afx x Ms -> Bs[buf]
      bf16x8 mb0 = *(const bf16x8*)((const char*)Ms + (k * 32 + lw) * 80 + (((lg ^ msw2) & 3) << 4));
      bf16x8 mb1 = *(const bf16x8*)((const char*)Ms + (k * 32 + 16 + lw) * 80 + (((lg ^ msw2) & 3) << 4));
      #pragma unroll
      for (int rt = 0; rt < 2; ++rt) {
        f32x4 d0 = __builtin_amdgcn_mfma_f32_16x16x32_bf16(afx[rt], mb0, z4, 0, 0, 0);
        f32x4 d1 = __builtin_amdgcn_mfma_f32_16x16x32_bf16(afx[rt], mb1, z4, 0, 0, 0);
        int rbase = wv * 32 + rt * 16 + (lg << 2);
        int dt = rbase >> 6, ci0 = rbase & 63;
        int r0 = dt * 32 + lw;
        int g0 = ((ci0 >> 3) ^ (r0 & 7)) & 7;
        char* c0 = (char*)(Bs + buf) + r0 * 128 + (g0 << 4) + ((ci0 << 1) & 15);
        *(unsigned*)(c0)     = packbf(d0[0], d0[1]);
        *(unsigned*)(c0 + 4) = packbf(d0[2], d0[3]);
        char* c1 = (char*)(Bs + buf) + (r0 + 16) * 128 + (g0 << 4) + ((ci0 << 1) & 15);
        *(unsigned*)(c1)     = packbf(d1[0], d1[1]);
        *(unsigned*)(c1 + 4) = packbf(d1[2], d1[3]);
      }
      __syncthreads();   // Bs[buf] ready (the ONLY barrier per step; dbuf covers rest)

      // MFMA#2 kk=0 (prefetched A-frags)
      __builtin_amdgcn_s_setprio(1);
      {
        bf16x8 bf2[4];
        #pragma unroll
        for (int j = 0; j < 4; ++j) {
          int rr = n_base + j * 16 + lw;
          int gg = (lg ^ (rr & 7)) & 7;
          bf2[j] = *(const bf16x8*)((const char*)(Bs + buf) + rr * 128 + (gg << 4));
        }
        #pragma unroll
        for (int i = 0; i < 4; ++i)
          #pragma unroll
          for (int j = 0; j < 4; ++j)
            acc[i][j] = __builtin_amdgcn_mfma_f32_16x16x32_bf16(af2a[i], bf2[j], acc[i][j], 0, 0, 0);
      }
      // MFMA#2 kk=1 (A-frags loaded at use; TLP covers the L2 latency)
      {
        bf16x8 af2b[4];
        #pragma unroll
        for (int i = 0; i < 4; ++i)
          af2b[i] = *(const bf16x8*)(wpS + ((i * 128 + 64) << 3));
        bf16x8 bf2[4];
        #pragma unroll
        for (int j = 0; j < 4; ++j) {
          int rr = n_base + j * 16 + lw;
          int gg = ((4 + lg) ^ (rr & 7)) & 7;
          bf2[j] = *(const bf16x8*)((const char*)(Bs + buf) + rr * 128 + (gg << 4));
        }
        #pragma unroll
        for (int i = 0; i < 4; ++i)
          #pragma unroll
          for (int j = 0; j < 4; ++j)
            acc[i][j] = __builtin_amdgcn_mfma_f32_16x16x32_bf16(af2b[i], bf2[j], acc[i][j], 0, 0, 0);
      }
      __builtin_amdgcn_s_setprio(0);
      // (no end-of-step barrier: dbuf invariant proves safety)
    }
  }

  // ---- epilogue: LDS-bounce dense writes (bias folded at eb-write) ----------
  __syncthreads();   // all #2 reads of Bs complete
  float* eb = (float*)Bs;   // 64 x 100 f32 = 25.6 KB
  #pragma unroll 1
  for (int rnd = 0; rnd < 4; ++rnd) {
    if ((wv >> 1) == rnd) {
      #pragma unroll
      for (int j = 0; j < 4; ++j) {
        int col = n_base + j * 16 + lw;
        int dt = col >> 5, w = col & 31;
        if (w < VV) {
          const float* brow = biasmat + (n * 25 + w) * 256 + rnd * 64;
          #pragma unroll
          for (int i = 0; i < 4; ++i) {
            #pragma unroll
            for (int r = 0; r < 4; ++r) {
              int cl = i * 16 + (lg << 2) + r;
              eb[cl * 100 + dt * 25 + w] = acc[i][j][r] + brow[cl];
            }
          }
        }
      }
    }
    __syncthreads();
    #pragma unroll
    for (int it = 0; it < 4; ++it) {
      int idx = it * 512 + tid;
      if (idx < 1600) {
        int cl = idx / 25, f4 = idx - cl * 25;
        f32x4 val = *(const f32x4*)(eb + cl * 100 + f4 * 4);
        *(f32x4*)(out + (long)n * 409600 + (long)(rnd * 64 + cl) * 1600
                      + t0 * 25 + f4 * 4) = val;
      }
    }
    __syncthreads();   // eb free for next round
  }
}

// ---------------- ws-free fp32 fallback (insurance) ----------------
__global__ __launch_bounds__(256) void fallback_kernel(
    const float* __restrict__ x, const float* __restrict__ A,
    const float* __restrict__ Bm, const float* __restrict__ lam_p,
    const float* __restrict__ W, const float* __restrict__ bvec,
    float* __restrict__ out)
{
  __shared__ __align__(16) float xs[CIN][28];
  __shared__ __align__(16) float Ms[KNUM][VV][28];   // [k][v][w] padded
  const int nt = blockIdx.x;
  const int n = nt >> 6, t = nt & 63;
  const int tid = threadIdx.x;
  const float lam = lam_p[0];

  const float* xp = x + (((long)(n * CIN + tid) * TDIM + t) * VV);
  #pragma unroll
  for (int v = 0; v < VV; ++v) xs[tid][v] = xp[v];
  xs[tid][25] = xs[tid][26] = xs[tid][27] = 0.f;
  for (int i = tid; i < KNUM * VV * VV; i += 256) {
    int k = i / (VV * VV);
    int r = i - k * VV * VV;
    int v = r / VV;
    int w = r - v * VV;
    Ms[k][v][w] = (k < ET) ? A[(k * VV + v) * VV + w]
                           : lam * Bm[(((n * ET) + (k - ET)) * VV + v) * VV + w];
    if (w == 24) { Ms[k][v][25] = Ms[k][v][26] = Ms[k][v][27] = 0.f; }
  }
  __syncthreads();

  float oacc[28] = {};
  for (int k = 0; k < KNUM; ++k) {
    float yv[28];
    float bv = bvec[(k << 8) + tid];
    #pragma unroll
    for (int v = 0; v < 28; ++v) yv[v] = 0.f;
    for (int ci = 0; ci < CIN; ++ci) {
      float wl = W[ci * KD + (k << 8) + tid];
      const f32x4* x4 = (const f32x4*)&xs[ci][0];
      #pragma unroll
      for (int q = 0; q < 7; ++q) {
        f32x4 xv = x4[q];
        yv[q*4+0] += wl*xv[0]; yv[q*4+1] += wl*xv[1];
        yv[q*4+2] += wl*xv[2]; yv[q*4+3] += wl*xv[3];
      }
    }
    #pragma unroll
    for (int v = 0; v < VV; ++v) {
      float yvv = yv[v] + bv;
      const f32x4* m4 = (const f32x4*)&Ms[k][v][0];
      #pragma unroll
      for (int q = 0; q < 7; ++q) {
        f32x4 mv = m4[q];
        oacc[q*4+0] += yvv*mv[0]; oacc[q*4+1] += yvv*mv[1];
        oacc[q*4+2] += yvv*mv[2]; oacc[q*4+3] += yvv*mv[3];
      }
    }
  }
  float* op = out + (((long)(n * COUT + tid) * TDIM + t) * VV);
  #pragma unroll
  for (int w = 0; w < VV; ++w) op[w] = oacc[w];
}

__global__ void copyA_kernel(const float* __restrict__ A, float* __restrict__ outA) {
  int i = blockIdx.x * 256 + threadIdx.x;
  if (i < ACNT) outA[i] = A[i];
}

extern "C" void kernel_launch(void* const* d_in, const int* in_sizes, int n_in,
                              void* d_out, int out_size, void* d_ws, size_t ws_size,
                              hipStream_t stream) {
  const float* x   = (const float*)d_in[0];
  const float* A   = (const float*)d_in[1];
  const float* Bm  = (const float*)d_in[2];
  const float* lam = (const float*)d_in[3];
  const float* W   = (const float*)d_in[4];
  const float* bv  = (const float*)d_in[5];
  float* out = (float*)d_out;

  if (d_ws != nullptr && ws_size >= WS_NEED) {
    bf16_t* wp3     = (bf16_t*)d_ws;
    float*  biasmat = (float*)((char*)d_ws + BIAS_OFF);
    constexpr int PREP_ITEMS = WP3_CHUNKS + NB * VV * COUT + ACNT;
    prep_kernel<<<(PREP_ITEMS + 255) / 256, 256, 0, stream>>>(A, Bm, lam, W, bv, wp3, biasmat, out + OUT0);
    fused_kernel<<<NB * 16, 512, 0, stream>>>(x, A, Bm, lam, wp3, biasmat, out);
  } else {
    fallback_kernel<<<NB * TDIM, 256, 0, stream>>>(x, A, Bm, lam, W, bv, out);
    copyA_kernel<<<(ACNT + 255) / 256, 256, 0, stream>>>(A, out + OUT0);
  }
}